// Round 12
// baseline (18641.214 us; speedup 1.0000x reference)
//
#include <hip/hip_runtime.h>
#include <math.h>

#define QQ 512
#define NN 1000
#define HHID 1024
#define HPAD 1024   // padded row stride for h trajectories (X uses 1024 too)
#define CCON 128
#define G4 4000
#define LAYERS 8
#define LBLK 63         // blocks per layer, 1024 thr, 1 neuron/wave
#define LPL 4           // layers per launch
#define NGRP (QQ / 4)   // gate groups of 4 timesteps

__device__ inline float wred_min(float v){ for(int o=32;o;o>>=1) v=fminf(v,__shfl_xor(v,o)); return v; }
__device__ inline float wred_max(float v){ for(int o=32;o;o>>=1) v=fmaxf(v,__shfl_xor(v,o)); return v; }
__device__ inline float wred_sum(float v){ for(int o=32;o;o>>=1) v+=__shfl_xor(v,o); return v; }

// ---------------- generic NT GEMM (X prologue only) ----------------
__global__ __launch_bounds__(256) void gemm_nt(
    const float* __restrict__ A, const float* __restrict__ B,
    const float* __restrict__ bias1,
    float* __restrict__ C, int M, int K, int R, int lda, int ldc) {
  __shared__ float As[16][65];
  __shared__ float Bs[16][65];
  int tid = threadIdx.x;
  int tx = tid & 15, ty = tid >> 4;
  int m0 = blockIdx.y * 64, r0 = blockIdx.x * 64;
  float acc[4][4] = {};
  for (int k0 = 0; k0 < K; k0 += 16) {
#pragma unroll
    for (int i = 0; i < 4; i++) {
      int idx = tid + 256 * i;
      int ml = idx >> 4, kl = idx & 15;
      int m = m0 + ml, k = k0 + kl;
      As[kl][ml] = (m < M && k < K) ? A[(size_t)m * lda + k] : 0.f;
      int r = r0 + ml;
      Bs[kl][ml] = (r < R && k < K) ? B[(size_t)r * K + k] : 0.f;
    }
    __syncthreads();
#pragma unroll
    for (int kk = 0; kk < 16; kk++) {
      float a[4], b[4];
#pragma unroll
      for (int i = 0; i < 4; i++) a[i] = As[kk][ty * 4 + i];
#pragma unroll
      for (int j = 0; j < 4; j++) b[j] = Bs[kk][tx * 4 + j];
#pragma unroll
      for (int i = 0; i < 4; i++)
#pragma unroll
        for (int j = 0; j < 4; j++) acc[i][j] += a[i] * b[j];
    }
    __syncthreads();
  }
#pragma unroll
  for (int i = 0; i < 4; i++) {
    int m = m0 + ty * 4 + i;
    if (m >= M) continue;
#pragma unroll
    for (int j = 0; j < 4; j++) {
      int r = r0 + tx * 4 + j;
      if (r >= R) continue;
      float v = acc[i][j];
      if (bias1) v += bias1[r];
      C[(size_t)m * ldc + r] = v;
    }
  }
}

// ------------- resident-layer diagonal pipeline (4 layers / launch) -------
// 252 blocks (1/CU, all co-resident). Block = (layer li, blk). Wave owns
// neuron n = blk*16+wave with its 4 W_hh rows in 64 pinned VGPRs for ALL
// 512 steps (preload once). Gates: every 4 steps, wait prev-layer flag >=
// r0+4, stage 4 Hin rows to LDS, stream W_ih from LLC (4-row reuse per
// load), keep 16 gate values in statically-indexed registers. Recurrence:
// round-10 proven sync (wave-0 flag poll + LDS go release, relaxed sc1
// atomics, NO fences -- agent acquire fence = buffer_inv = L2 inval).
struct LayerDesc {
  const float* Hin; const float* Wih; const float* bih; const float* bhh;
  const float* Whh; float* Hout; int* flagOwn; int* flagPrev;
  int kin; int hasPrev;
};
struct PipeArgs { LayerDesc L[LPL]; };

__global__ __launch_bounds__(1024, 4) void lstm_pipe4(PipeArgs args) {
  int li = blockIdx.x / LBLK;
  int blk = blockIdx.x - li * LBLK;
  LayerDesc ld = args.L[li];
  __shared__ float hs[1024];
  __shared__ float xr[4][1024];
  __shared__ int go[QQ];
  __shared__ int goG[NGRP];
  int tid = threadIdx.x;
  int wave = tid >> 6, lane = tid & 63;
  int n = blk * 16 + wave;
  bool active = (n < NN);
  int kin = ld.kin;

  for (int i = tid; i < QQ; i += 1024) go[i] = 0;
  for (int i = tid; i < NGRP; i += 1024) goG[i] = 0;
  if (tid >= NN) hs[tid] = 0.f;  // zero pad once

  // Preload W_hh rows: whh[q][it] = Whh[q*1000+n][it*64+lane]
  float whh[4][16];
  if (active) {
#pragma unroll
    for (int q = 0; q < 4; q++) {
      const float* wr = ld.Whh + (size_t)(q * NN + n) * NN;
#pragma unroll
      for (int it = 0; it < 16; it++) {
        int k = it * 64 + lane;
        whh[q][it] = (k < NN) ? wr[k] : 0.f;
      }
    }
  } else {
#pragma unroll
    for (int q = 0; q < 4; q++)
#pragma unroll
      for (int it = 0; it < 16; it++) whh[q][it] = 0.f;
  }
#pragma unroll
  for (int q = 0; q < 4; q++)
#pragma unroll
    for (int it = 0; it < 16; it++)
      asm volatile("" : "+v"(whh[q][it]));  // pin register-resident

  float pb[4] = {0.f, 0.f, 0.f, 0.f};
  if (active) {
#pragma unroll
    for (int q = 0; q < 4; q++)
      pb[q] = ld.bih[q * NN + n] + ld.bhh[q * NN + n];
  }
  const float* w0 = ld.Wih + (size_t)(0 * NN + n) * kin;
  const float* w1 = ld.Wih + (size_t)(1 * NN + n) * kin;
  const float* w2 = ld.Wih + (size_t)(2 * NN + n) * kin;
  const float* w3 = ld.Wih + (size_t)(3 * NN + n) * kin;
  __syncthreads();  // go/goG/hs-pad init visible

  float creg = 0.f;

  for (int k = 0; k < NGRP; k++) {
    int r0 = 4 * k;
    // ---- gate-group wait on prev layer: need flagPrev >= r0+4 ----
    if (ld.hasPrev) {
      int need = r0 + 4;
      if (wave == 0) {
        for (;;) {
          int v = need;
          if (lane < LBLK)
            v = __hip_atomic_load(&ld.flagPrev[lane], __ATOMIC_RELAXED,
                                  __HIP_MEMORY_SCOPE_AGENT);
          if (__all(v >= need)) break;
          __builtin_amdgcn_s_sleep(2);
        }
        if (lane == 0)
          __hip_atomic_store(&goG[k], 1, __ATOMIC_RELAXED,
                             __HIP_MEMORY_SCOPE_WORKGROUP);
      } else {
        while (__hip_atomic_load(&goG[k], __ATOMIC_RELAXED,
                                 __HIP_MEMORY_SCOPE_WORKGROUP) == 0)
          __builtin_amdgcn_s_sleep(1);
      }
    }
    // ---- stage 4 input rows (fully available once prev flag seen) ----
#pragma unroll
    for (int j = 0; j < 4; j++) {
      float v = 0.f;
      if (tid < kin)
        v = __hip_atomic_load(&ld.Hin[(size_t)(r0 + j) * HPAD + tid],
                              __ATOMIC_RELAXED, __HIP_MEMORY_SCOPE_AGENT);
      xr[j][tid] = v;
    }
    __syncthreads();
    // ---- gate dot: stream W_ih (one load feeds 4 rows) ----
    float gA0[4], gA1[4], gA2[4], gA3[4];  // [q] per step j=0..3
    if (active) {
      float a0[4] = {}, a1[4] = {}, a2[4] = {}, a3[4] = {};
#pragma unroll
      for (int it = 0; it < 16; it++) {
        int kk = it * 64 + lane;
        int kc = kk < kin ? kk : 0;  // clamp (xv pad is 0 anyway)
        float v0 = w0[kc], v1 = w1[kc], v2 = w2[kc], v3 = w3[kc];
        float x0 = xr[0][kk], x1 = xr[1][kk], x2 = xr[2][kk], x3 = xr[3][kk];
        a0[0] += v0 * x0; a0[1] += v1 * x0; a0[2] += v2 * x0; a0[3] += v3 * x0;
        a1[0] += v0 * x1; a1[1] += v1 * x1; a1[2] += v2 * x1; a1[3] += v3 * x1;
        a2[0] += v0 * x2; a2[1] += v1 * x2; a2[2] += v2 * x2; a2[3] += v3 * x2;
        a3[0] += v0 * x3; a3[1] += v1 * x3; a3[2] += v2 * x3; a3[3] += v3 * x3;
      }
#pragma unroll
      for (int q = 0; q < 4; q++) {
#pragma unroll
        for (int o = 32; o; o >>= 1) {
          a0[q] += __shfl_xor(a0[q], o);
          a1[q] += __shfl_xor(a1[q], o);
          a2[q] += __shfl_xor(a2[q], o);
          a3[q] += __shfl_xor(a3[q], o);
        }
        gA0[q] = a0[q] + pb[q]; gA1[q] = a1[q] + pb[q];
        gA2[q] = a2[q] + pb[q]; gA3[q] = a3[q] + pb[q];
      }
    }
    // ---- 4 recurrence steps ----
#pragma unroll
    for (int j = 0; j < 4; j++) {
      int t = r0 + j;
      if (t > 0) {
        if (wave == 0) {
          for (;;) {
            int v = t;
            if (lane < LBLK)
              v = __hip_atomic_load(&ld.flagOwn[lane], __ATOMIC_RELAXED,
                                    __HIP_MEMORY_SCOPE_AGENT);
            if (__all(v >= t)) break;
            __builtin_amdgcn_s_sleep(2);
          }
          if (lane == 0)
            __hip_atomic_store(&go[t], 1, __ATOMIC_RELAXED,
                               __HIP_MEMORY_SCOPE_WORKGROUP);
        } else {
          while (__hip_atomic_load(&go[t], __ATOMIC_RELAXED,
                                   __HIP_MEMORY_SCOPE_WORKGROUP) == 0)
            __builtin_amdgcn_s_sleep(1);
        }
        if (tid < NN)
          hs[tid] = __hip_atomic_load(&ld.Hout[(size_t)(t - 1) * HPAD + tid],
                                      __ATOMIC_RELAXED,
                                      __HIP_MEMORY_SCOPE_AGENT);
        __syncthreads();
      }
      if (active) {
        float g0 = (j == 0) ? gA0[0] : (j == 1) ? gA1[0] : (j == 2) ? gA2[0] : gA3[0];
        float g1 = (j == 0) ? gA0[1] : (j == 1) ? gA1[1] : (j == 2) ? gA2[1] : gA3[1];
        float g2 = (j == 0) ? gA0[2] : (j == 1) ? gA1[2] : (j == 2) ? gA2[2] : gA3[2];
        float g3 = (j == 0) ? gA0[3] : (j == 1) ? gA1[3] : (j == 2) ? gA2[3] : gA3[3];
        if (t > 0) {
          float b0 = 0.f, b1 = 0.f, b2 = 0.f, b3 = 0.f;
#pragma unroll
          for (int it = 0; it < 16; it++) {
            float hv = hs[it * 64 + lane];
            b0 += whh[0][it] * hv;
            b1 += whh[1][it] * hv;
            b2 += whh[2][it] * hv;
            b3 += whh[3][it] * hv;
          }
#pragma unroll
          for (int o = 32; o; o >>= 1) {
            b0 += __shfl_xor(b0, o);
            b1 += __shfl_xor(b1, o);
            b2 += __shfl_xor(b2, o);
            b3 += __shfl_xor(b3, o);
          }
          g0 += b0; g1 += b1; g2 += b2; g3 += b3;
        }
        float ii = 1.f / (1.f + expf(-g0));
        float ff = 1.f / (1.f + expf(-g1));
        float gg = tanhf(g2);
        float oo = 1.f / (1.f + expf(-g3));
        creg = ff * creg + ii * gg;
        float h = oo * tanhf(creg);
        if (lane == 0)
          __hip_atomic_store(&ld.Hout[(size_t)t * HPAD + n], h,
                             __ATOMIC_RELAXED, __HIP_MEMORY_SCOPE_AGENT);
      }
      asm volatile("s_waitcnt vmcnt(0)" ::: "memory");  // h store acked
      __syncthreads();  // all waves drained before publish
      if (tid == 0)
        __hip_atomic_store(&ld.flagOwn[blk], t + 1, __ATOMIC_RELAXED,
                           __HIP_MEMORY_SCOPE_AGENT);
    }
  }
}

// ---------------- epilogue ----------------
__global__ __launch_bounds__(256) void epilogue_out(
    const float* __restrict__ H7,   // [QQ, HPAD]
    const float* __restrict__ Wlin, const float* __restrict__ blin,
    const int* __restrict__ ccol, const float* __restrict__ Dnz,
    float* __restrict__ out,        // [QQ, NN]
    float* __restrict__ irbuf, float* __restrict__ mnirbuf) {
  int t = blockIdx.x, tid = threadIdx.x;
  int wave = tid >> 6, lane = tid & 63;
  __shared__ float hbuf[NN];
  __shared__ float smin[4], smax[4];
  __shared__ float bc[2];
  float lmin = 3.4e38f, lmax = -3.4e38f;
  for (int i = tid; i < NN; i += 256) {
    float v = H7[(size_t)t * HPAD + i];
    hbuf[i] = v;
    lmin = fminf(lmin, v); lmax = fmaxf(lmax, v);
  }
  lmin = wred_min(lmin); lmax = wred_max(lmax);
  if (lane == 0) { smin[wave] = lmin; smax[wave] = lmax; }
  __syncthreads();
  if (tid == 0) {
    bc[0] = fminf(fminf(smin[0], smin[1]), fminf(smin[2], smin[3]));
    bc[1] = fmaxf(fmaxf(smax[0], smax[1]), fmaxf(smax[2], smax[3]));
  }
  __syncthreads();
  float hmn = bc[0], hmx = bc[1];
  float clo = 3.4e38f, chi = -3.4e38f;
  if (tid < CCON) {
    float w = Wlin[tid], b = blin[tid];
    clo = b + fminf(w * hmn, w * hmx);
    chi = b + fmaxf(w * hmn, w * hmx);
  }
  clo = wred_min(clo); chi = wred_max(chi);
  __syncthreads();  // smin/smax reused below
  if (lane == 0) { smin[wave] = clo; smax[wave] = chi; }
  __syncthreads();
  if (tid == 0) {
    float mn = fminf(fminf(smin[0], smin[1]), fminf(smin[2], smin[3]));
    float mx = fmaxf(fmaxf(smax[0], smax[1]), fmaxf(smax[2], smax[3]));
    float ir = 1.f / (mx - mn);
    bc[0] = mn; bc[1] = ir;
    irbuf[t] = ir;
    mnirbuf[t] = mn * ir;
  }
  __syncthreads();
  float mn = bc[0], ir = bc[1];
  int cc = ccol[t];
  float wcc = Wlin[cc], bcc = blin[cc], d = Dnz[t];
  for (int n = tid; n < NN; n += 256) {
    float s = (hbuf[n] * wcc + bcc - mn) * ir;
    out[(size_t)t * NN + n] = fmaxf(0.25f, 1.f - expf(-10.f * (s - d)));
  }
}

__global__ void reduce_scalars(const float* __restrict__ ir,
                               const float* __restrict__ mnir,
                               float* __restrict__ scal) {
  int tid = threadIdx.x;  // 512
  int wave = tid >> 6, lane = tid & 63;
  __shared__ float s1[8], s2[8];
  float a = ir[tid], b = mnir[tid];
  a = wred_sum(a); b = wred_sum(b);
  if (lane == 0) { s1[wave] = a; s2[wave] = b; }
  __syncthreads();
  if (tid == 0) {
    float A = 0.f, B = 0.f;
    for (int i = 0; i < 8; i++) { A += s1[i]; B += s2[i]; }
    scal[0] = A; scal[1] = B;
  }
}

__global__ void accum_A(const float* __restrict__ H7,
                        const float* __restrict__ ir,
                        float* __restrict__ Avec) {
  int n = blockIdx.x * 256 + threadIdx.x;
  if (n < NN) {
    float acc = 0.f;
    for (int t = 0; t < QQ; t++) acc += H7[(size_t)t * HPAD + n] * ir[t];
    Avec[n] = acc;
  }
}

__global__ void skills_out(const float* __restrict__ Avec,
                           const float* __restrict__ Wlin,
                           const float* __restrict__ blin,
                           const float* __restrict__ scal,
                           float* __restrict__ out) {  // [NN, CCON]
  int idx = blockIdx.x * 256 + threadIdx.x;
  if (idx < NN * CCON) {
    int n = idx >> 7, c = idx & 127;
    out[idx] = (Wlin[c] * Avec[n] + blin[c] * scal[0] - scal[1]) * (1.f / (float)QQ);
  }
}

extern "C" void kernel_launch(void* const* d_in, const int* in_sizes, int n_in,
                              void* d_out, int out_size, void* d_ws, size_t ws_size,
                              hipStream_t stream) {
  const float* inputs = (const float*)d_in[0];
  const int*   ccol   = (const int*)d_in[1];
  const float* W_inp  = (const float*)d_in[2];
  const float* b_inp  = (const float*)d_in[3];
  const float* W_ih0  = (const float*)d_in[4];
  const float* W_hh0  = (const float*)d_in[5];
  const float* b_ih0  = (const float*)d_in[6];
  const float* b_hh0  = (const float*)d_in[7];
  const float* W_ih   = (const float*)d_in[8];   // [7, 4000, 1000]
  const float* W_hh   = (const float*)d_in[9];   // [7, 4000, 1000]
  const float* b_ih   = (const float*)d_in[10];  // [7, 4000]
  const float* b_hh   = (const float*)d_in[11];  // [7, 4000]
  const float* W_lin  = (const float*)d_in[12];  // [128]
  const float* b_lin  = (const float*)d_in[13];  // [128]
  const float* D_nz   = (const float*)d_in[14];  // [512]

  float* ws = (float*)d_ws;
  float* X    = ws;                           // [512,1024] padded rows
  float* H    = X + (size_t)QQ * HPAD;        // [8][512][1024]
  float* irb  = H + (size_t)LAYERS * QQ * HPAD; // [512]
  float* mnir = irb + QQ;                     // [512]
  float* Avec = mnir + QQ;                    // [1024]
  float* scal = Avec + 1024;                  // [2] (+pad)
  int*   flags = (int*)(scal + 16);           // [8*64] stamped flags

  float* out_main   = (float*)d_out;            // [512,1000]
  float* out_skills = (float*)d_out + QQ * NN;  // [1000,128]

  // Zero all layer flags (captured in graph; re-zeroed every replay).
  hipMemsetAsync(flags, 0, LAYERS * 64 * sizeof(int), stream);

  // X = inputs @ W_inp^T + b_inp   (M=512, K=1000, R=1024, ldc=HPAD)
  gemm_nt<<<dim3(HPAD / 64, QQ / 64), 256, 0, stream>>>(
      inputs, W_inp, b_inp, X, QQ, NN, HPAD, NN, HPAD);

  // Two resident-layer pipeline launches: layers 0-3, then 4-7 (launch 2's
  // prev-layer flags are fully stamped by launch 1).
  for (int base = 0; base < LAYERS; base += LPL) {
    PipeArgs pa;
    for (int i = 0; i < LPL; i++) {
      int l = base + i;
      LayerDesc& d = pa.L[i];
      if (l == 0) {
        d.Hin = X; d.Wih = W_ih0; d.bih = b_ih0; d.bhh = b_hh0;
        d.Whh = W_hh0; d.kin = HHID; d.hasPrev = 0; d.flagPrev = flags;
      } else {
        d.Hin = H + (size_t)(l - 1) * QQ * HPAD;
        d.Wih = W_ih + (size_t)(l - 1) * G4 * NN;
        d.bih = b_ih + (size_t)(l - 1) * G4;
        d.bhh = b_hh + (size_t)(l - 1) * G4;
        d.Whh = W_hh + (size_t)(l - 1) * G4 * NN;
        d.kin = NN; d.hasPrev = 1;
        d.flagPrev = flags + (l - 1) * 64;
      }
      d.Hout = H + (size_t)l * QQ * HPAD;
      d.flagOwn = flags + l * 64;
    }
    lstm_pipe4<<<LPL * LBLK, 1024, 0, stream>>>(pa);
  }

  float* H7 = H + (size_t)7 * QQ * HPAD;
  epilogue_out<<<QQ, 256, 0, stream>>>(H7, W_lin, b_lin, ccol, D_nz,
                                       out_main, irb, mnir);
  reduce_scalars<<<1, 512, 0, stream>>>(irb, mnir, scal);
  accum_A<<<4, 256, 0, stream>>>(H7, irb, Avec);
  skills_out<<<(NN * CCON) / 256, 256, 0, stream>>>(Avec, W_lin, b_lin, scal,
                                                    out_skills);
}

// Round 13
// 8936.642 us; speedup vs baseline: 2.0859x; 2.0859x over previous
//
#include <hip/hip_runtime.h>
#include <math.h>

#define QQ 512
#define NN 1000
#define HHID 1024
#define HPAD 1024   // padded row stride for h trajectories (X uses 1024 too)
#define CCON 128
#define G4 4000
#define LAYERS 8
#define TC 64                       // timestep chunk
#define CHUNKS (QQ / TC)            // 8
#define CONC 4      // max concurrent pairs: 252x1024-thr blocks = 1 round
#define LBLK 63     // blocks per pair, 1024 thr, 1 neuron/wave

__device__ inline float wred_min(float v){ for(int o=32;o;o>>=1) v=fminf(v,__shfl_xor(v,o)); return v; }
__device__ inline float wred_max(float v){ for(int o=32;o;o>>=1) v=fmaxf(v,__shfl_xor(v,o)); return v; }
__device__ inline float wred_sum(float v){ for(int o=32;o;o>>=1) v+=__shfl_xor(v,o); return v; }

// Vectorized weight-row preload, lane-contiguous partition: dst[i] holds
// W[row][lane*16+i]. Rows are 16B-aligned (kin*4 is a multiple of 16).
// Plain (non-sc1) loads are legal: weights are kernel inputs.
__device__ inline void load_row16(float dst[16], const float* __restrict__ row,
                                  int kin, int lane) {
  int k0 = lane * 16;
  if (k0 + 15 < kin) {
    const float4* p = (const float4*)(row + k0);
    float4 a = p[0], b = p[1], c = p[2], d = p[3];
    dst[0]=a.x; dst[1]=a.y; dst[2]=a.z; dst[3]=a.w;
    dst[4]=b.x; dst[5]=b.y; dst[6]=b.z; dst[7]=b.w;
    dst[8]=c.x; dst[9]=c.y; dst[10]=c.z; dst[11]=c.w;
    dst[12]=d.x; dst[13]=d.y; dst[14]=d.z; dst[15]=d.w;
  } else {
#pragma unroll
    for (int i = 0; i < 16; i++) {
      int k = k0 + i;
      dst[i] = (k < kin) ? row[k] : 0.f;
    }
  }
}

// ---------------- generic NT GEMM (X prologue only) ----------------
__global__ __launch_bounds__(256) void gemm_nt(
    const float* __restrict__ A, const float* __restrict__ B,
    const float* __restrict__ bias1,
    float* __restrict__ C, int M, int K, int R, int lda, int ldc) {
  __shared__ float As[16][65];
  __shared__ float Bs[16][65];
  int tid = threadIdx.x;
  int tx = tid & 15, ty = tid >> 4;
  int m0 = blockIdx.y * 64, r0 = blockIdx.x * 64;
  float acc[4][4] = {};
  for (int k0 = 0; k0 < K; k0 += 16) {
#pragma unroll
    for (int i = 0; i < 4; i++) {
      int idx = tid + 256 * i;
      int ml = idx >> 4, kl = idx & 15;
      int m = m0 + ml, k = k0 + kl;
      As[kl][ml] = (m < M && k < K) ? A[(size_t)m * lda + k] : 0.f;
      int r = r0 + ml;
      Bs[kl][ml] = (r < R && k < K) ? B[(size_t)r * K + k] : 0.f;
    }
    __syncthreads();
#pragma unroll
    for (int kk = 0; kk < 16; kk++) {
      float a[4], b[4];
#pragma unroll
      for (int i = 0; i < 4; i++) a[i] = As[kk][ty * 4 + i];
#pragma unroll
      for (int j = 0; j < 4; j++) b[j] = Bs[kk][tx * 4 + j];
#pragma unroll
      for (int i = 0; i < 4; i++)
#pragma unroll
        for (int j = 0; j < 4; j++) acc[i][j] += a[i] * b[j];
    }
    __syncthreads();
  }
#pragma unroll
  for (int i = 0; i < 4; i++) {
    int m = m0 + ty * 4 + i;
    if (m >= M) continue;
#pragma unroll
    for (int j = 0; j < 4; j++) {
      int r = r0 + tx * 4 + j;
      if (r >= R) continue;
      float v = acc[i][j];
      if (bias1) v += bias1[r];
      C[(size_t)m * ldc + r] = v;
    }
  }
}

// ---------------- fused per-stage recurrence (gates + TC steps) ----------
// Round-11 structure with all cross-dispatch loads vectorized (float4) and
// the dot repartitioned lane-contiguous (k = lane*16+i): weight preloads
// become 4x dwordx4/lane, LDS fragment reads become b128 (2-way bank alias,
// free). sc1 only where required: intra-dispatch h gather + flags.
struct RPair { const float* Hin; const float* Wih; const float* b1;
               const float* b2; const float* Whh; float* Hout; int* flag;
               float* Call; int t0; int kin; };
struct RArgs { RPair p[CONC]; };

__global__ __launch_bounds__(1024, 4) void lstm_stage(RArgs args) {
  RPair rp = args.p[blockIdx.y];
  __shared__ __align__(16) float hst[4][1024];  // Phase A row staging
  __shared__ float gl[TC * 64];   // gates: gl[tt*64 + q*16 + w]
  __shared__ __align__(16) float hs[1024];      // Phase B h broadcast
  __shared__ int go[TC];
  int tid = threadIdx.x;
  int wave = tid >> 6, lane = tid & 63;
  int n = blockIdx.x * 16 + wave;
  bool active = (n < NN);
  int kin = rp.kin;               // 1024 for layer 0 (X), 1000 otherwise
  int t0 = rp.t0;

  float wreg[4][16];
  float pb[4] = {0.f, 0.f, 0.f, 0.f};

  // ---- Phase A: input-side gates ----
  if (active) {
#pragma unroll
    for (int q = 0; q < 4; q++) {
      load_row16(wreg[q], rp.Wih + (size_t)(q * NN + n) * kin, kin, lane);
      pb[q] = rp.b1[q * NN + n] + rp.b2[q * NN + n];
    }
  } else {
#pragma unroll
    for (int q = 0; q < 4; q++)
#pragma unroll
      for (int it = 0; it < 16; it++) wreg[q][it] = 0.f;
  }
  {
    int jrow = tid >> 8, c4 = tid & 255;
    for (int tt0 = 0; tt0 < TC; tt0 += 4) {
      // stage 4 rows vectorized: 1 float4 per thread (prev-dispatch data,
      // plain loads legal)
      {
        const float* rowp = rp.Hin + (size_t)(t0 + tt0 + jrow) * HPAD;
        float4 v = ((const float4*)rowp)[c4];
        if (kin < 1024 && c4 * 4 + 3 >= kin) {
          float* f = (float*)&v;
#pragma unroll
          for (int e = 0; e < 4; e++) if (c4 * 4 + e >= kin) f[e] = 0.f;
        }
        *((float4*)&hst[jrow][c4 * 4]) = v;
      }
      __syncthreads();
      if (active) {
#pragma unroll
        for (int j = 0; j < 4; j++) {
          float a0 = 0.f, a1 = 0.f, a2 = 0.f, a3 = 0.f;
#pragma unroll
          for (int i = 0; i < 16; i += 4) {
            float4 hv = *((const float4*)&hst[j][lane * 16 + i]);
            a0 += wreg[0][i]*hv.x + wreg[0][i+1]*hv.y + wreg[0][i+2]*hv.z + wreg[0][i+3]*hv.w;
            a1 += wreg[1][i]*hv.x + wreg[1][i+1]*hv.y + wreg[1][i+2]*hv.z + wreg[1][i+3]*hv.w;
            a2 += wreg[2][i]*hv.x + wreg[2][i+1]*hv.y + wreg[2][i+2]*hv.z + wreg[2][i+3]*hv.w;
            a3 += wreg[3][i]*hv.x + wreg[3][i+1]*hv.y + wreg[3][i+2]*hv.z + wreg[3][i+3]*hv.w;
          }
#pragma unroll
          for (int o = 32; o; o >>= 1) {
            a0 += __shfl_xor(a0, o);
            a1 += __shfl_xor(a1, o);
            a2 += __shfl_xor(a2, o);
            a3 += __shfl_xor(a3, o);
          }
          if (lane == 0) {
            int tt = tt0 + j;
            gl[tt * 64 + wave] = a0 + pb[0];
            gl[tt * 64 + 16 + wave] = a1 + pb[1];
            gl[tt * 64 + 32 + wave] = a2 + pb[2];
            gl[tt * 64 + 48 + wave] = a3 + pb[3];
          }
        }
      }
      __syncthreads();
    }
  }

  // ---- Phase B: recurrence ----
  if (active) {
#pragma unroll
    for (int q = 0; q < 4; q++)
      load_row16(wreg[q], rp.Whh + (size_t)(q * NN + n) * NN, NN, lane);
  } else {
#pragma unroll
    for (int q = 0; q < 4; q++)
#pragma unroll
      for (int it = 0; it < 16; it++) wreg[q][it] = 0.f;
  }
#pragma unroll
  for (int q = 0; q < 4; q++)
#pragma unroll
    for (int it = 0; it < 16; it++)
      asm volatile("" : "+v"(wreg[q][it]));  // keep register-resident

  if (tid >= NN) hs[tid] = 0.f;
  if (tid < TC) go[tid] = 0;
  __syncthreads();

  float creg = 0.f;
  if (t0 > 0 && active) creg = rp.Call[n];  // prev-dispatch data, plain load

  for (int tt = 0; tt < TC; tt++) {
    int t = t0 + tt;
    if (t > 0) {
      if (wave == 0) {
        for (;;) {
          int v = t;
          if (lane < LBLK)
            v = __hip_atomic_load(&rp.flag[lane], __ATOMIC_RELAXED,
                                  __HIP_MEMORY_SCOPE_AGENT);
          if (__all(v >= t)) break;
          __builtin_amdgcn_s_sleep(2);
        }
        if (lane == 0)
          __hip_atomic_store(&go[tt], 1, __ATOMIC_RELAXED,
                             __HIP_MEMORY_SCOPE_WORKGROUP);
      } else {
        while (__hip_atomic_load(&go[tt], __ATOMIC_RELAXED,
                                 __HIP_MEMORY_SCOPE_WORKGROUP) == 0)
          __builtin_amdgcn_s_sleep(1);
      }
      if (tid < NN)  // intra-dispatch cross-block: sc1 required
        hs[tid] = __hip_atomic_load(&rp.Hout[(size_t)(t - 1) * HPAD + tid],
                                    __ATOMIC_RELAXED, __HIP_MEMORY_SCOPE_AGENT);
      __syncthreads();
    }
    if (active) {
      float g0 = gl[tt * 64 + wave];
      float g1 = gl[tt * 64 + 16 + wave];
      float g2 = gl[tt * 64 + 32 + wave];
      float g3 = gl[tt * 64 + 48 + wave];
      if (t > 0) {
        float a0 = 0.f, a1 = 0.f, a2 = 0.f, a3 = 0.f;
#pragma unroll
        for (int i = 0; i < 16; i += 4) {
          float4 hv = *((const float4*)&hs[lane * 16 + i]);
          a0 += wreg[0][i]*hv.x + wreg[0][i+1]*hv.y + wreg[0][i+2]*hv.z + wreg[0][i+3]*hv.w;
          a1 += wreg[1][i]*hv.x + wreg[1][i+1]*hv.y + wreg[1][i+2]*hv.z + wreg[1][i+3]*hv.w;
          a2 += wreg[2][i]*hv.x + wreg[2][i+1]*hv.y + wreg[2][i+2]*hv.z + wreg[2][i+3]*hv.w;
          a3 += wreg[3][i]*hv.x + wreg[3][i+1]*hv.y + wreg[3][i+2]*hv.z + wreg[3][i+3]*hv.w;
        }
#pragma unroll
        for (int o = 32; o; o >>= 1) {
          a0 += __shfl_xor(a0, o);
          a1 += __shfl_xor(a1, o);
          a2 += __shfl_xor(a2, o);
          a3 += __shfl_xor(a3, o);
        }
        g0 += a0; g1 += a1; g2 += a2; g3 += a3;
      }
      float ii = 1.f / (1.f + expf(-g0));
      float ff = 1.f / (1.f + expf(-g1));
      float gg = tanhf(g2);
      float oo = 1.f / (1.f + expf(-g3));
      creg = ff * creg + ii * gg;
      float h = oo * tanhf(creg);
      if (lane == 0)
        __hip_atomic_store(&rp.Hout[(size_t)t * HPAD + n], h, __ATOMIC_RELAXED,
                           __HIP_MEMORY_SCOPE_AGENT);
    }
    asm volatile("s_waitcnt vmcnt(0)" ::: "memory");  // own h store acked
    __syncthreads();  // all waves' stores drained before publish
    if (tid == 0)
      __hip_atomic_store(&rp.flag[blockIdx.x], t + 1, __ATOMIC_RELAXED,
                         __HIP_MEMORY_SCOPE_AGENT);
  }
  if (active && lane == 0)
    __hip_atomic_store(&rp.Call[n], creg, __ATOMIC_RELAXED,
                       __HIP_MEMORY_SCOPE_AGENT);
}

// ---------------- epilogue ----------------
__global__ __launch_bounds__(256) void epilogue_out(
    const float* __restrict__ H7,   // [QQ, HPAD]
    const float* __restrict__ Wlin, const float* __restrict__ blin,
    const int* __restrict__ ccol, const float* __restrict__ Dnz,
    float* __restrict__ out,        // [QQ, NN]
    float* __restrict__ irbuf, float* __restrict__ mnirbuf) {
  int t = blockIdx.x, tid = threadIdx.x;
  int wave = tid >> 6, lane = tid & 63;
  __shared__ float hbuf[NN];
  __shared__ float smin[4], smax[4];
  __shared__ float bc[2];
  float lmin = 3.4e38f, lmax = -3.4e38f;
  for (int i = tid; i < NN; i += 256) {
    float v = H7[(size_t)t * HPAD + i];
    hbuf[i] = v;
    lmin = fminf(lmin, v); lmax = fmaxf(lmax, v);
  }
  lmin = wred_min(lmin); lmax = wred_max(lmax);
  if (lane == 0) { smin[wave] = lmin; smax[wave] = lmax; }
  __syncthreads();
  if (tid == 0) {
    bc[0] = fminf(fminf(smin[0], smin[1]), fminf(smin[2], smin[3]));
    bc[1] = fmaxf(fmaxf(smax[0], smax[1]), fmaxf(smax[2], smax[3]));
  }
  __syncthreads();
  float hmn = bc[0], hmx = bc[1];
  float clo = 3.4e38f, chi = -3.4e38f;
  if (tid < CCON) {
    float w = Wlin[tid], b = blin[tid];
    clo = b + fminf(w * hmn, w * hmx);
    chi = b + fmaxf(w * hmn, w * hmx);
  }
  clo = wred_min(clo); chi = wred_max(chi);
  __syncthreads();  // smin/smax reused below
  if (lane == 0) { smin[wave] = clo; smax[wave] = chi; }
  __syncthreads();
  if (tid == 0) {
    float mn = fminf(fminf(smin[0], smin[1]), fminf(smin[2], smin[3]));
    float mx = fmaxf(fmaxf(smax[0], smax[1]), fmaxf(smax[2], smax[3]));
    float ir = 1.f / (mx - mn);
    bc[0] = mn; bc[1] = ir;
    irbuf[t] = ir;
    mnirbuf[t] = mn * ir;
  }
  __syncthreads();
  float mn = bc[0], ir = bc[1];
  int cc = ccol[t];
  float wcc = Wlin[cc], bcc = blin[cc], d = Dnz[t];
  for (int n = tid; n < NN; n += 256) {
    float s = (hbuf[n] * wcc + bcc - mn) * ir;
    out[(size_t)t * NN + n] = fmaxf(0.25f, 1.f - expf(-10.f * (s - d)));
  }
}

__global__ void reduce_scalars(const float* __restrict__ ir,
                               const float* __restrict__ mnir,
                               float* __restrict__ scal) {
  int tid = threadIdx.x;  // 512
  int wave = tid >> 6, lane = tid & 63;
  __shared__ float s1[8], s2[8];
  float a = ir[tid], b = mnir[tid];
  a = wred_sum(a); b = wred_sum(b);
  if (lane == 0) { s1[wave] = a; s2[wave] = b; }
  __syncthreads();
  if (tid == 0) {
    float A = 0.f, B = 0.f;
    for (int i = 0; i < 8; i++) { A += s1[i]; B += s2[i]; }
    scal[0] = A; scal[1] = B;
  }
}

__global__ void accum_A(const float* __restrict__ H7,
                        const float* __restrict__ ir,
                        float* __restrict__ Avec) {
  int n = blockIdx.x * 256 + threadIdx.x;
  if (n < NN) {
    float acc = 0.f;
    for (int t = 0; t < QQ; t++) acc += H7[(size_t)t * HPAD + n] * ir[t];
    Avec[n] = acc;
  }
}

__global__ void skills_out(const float* __restrict__ Avec,
                           const float* __restrict__ Wlin,
                           const float* __restrict__ blin,
                           const float* __restrict__ scal,
                           float* __restrict__ out) {  // [NN, CCON]
  int idx = blockIdx.x * 256 + threadIdx.x;
  if (idx < NN * CCON) {
    int n = idx >> 7, c = idx & 127;
    out[idx] = (Wlin[c] * Avec[n] + blin[c] * scal[0] - scal[1]) * (1.f / (float)QQ);
  }
}

extern "C" void kernel_launch(void* const* d_in, const int* in_sizes, int n_in,
                              void* d_out, int out_size, void* d_ws, size_t ws_size,
                              hipStream_t stream) {
  const float* inputs = (const float*)d_in[0];
  const int*   ccol   = (const int*)d_in[1];
  const float* W_inp  = (const float*)d_in[2];
  const float* b_inp  = (const float*)d_in[3];
  const float* W_ih0  = (const float*)d_in[4];
  const float* W_hh0  = (const float*)d_in[5];
  const float* b_ih0  = (const float*)d_in[6];
  const float* b_hh0  = (const float*)d_in[7];
  const float* W_ih   = (const float*)d_in[8];   // [7, 4000, 1000]
  const float* W_hh   = (const float*)d_in[9];   // [7, 4000, 1000]
  const float* b_ih   = (const float*)d_in[10];  // [7, 4000]
  const float* b_hh   = (const float*)d_in[11];  // [7, 4000]
  const float* W_lin  = (const float*)d_in[12];  // [128]
  const float* b_lin  = (const float*)d_in[13];  // [128]
  const float* D_nz   = (const float*)d_in[14];  // [512]

  float* ws = (float*)d_ws;
  float* X    = ws;                           // [512,1024] padded rows
  float* H    = X + (size_t)QQ * HPAD;        // [8][512][1024]
  float* Call = H + (size_t)LAYERS * QQ * HPAD; // [8][1024]
  float* irb  = Call + LAYERS * HPAD;         // [512]
  float* mnir = irb + QQ;                     // [512]
  float* Avec = mnir + QQ;                    // [1024]
  float* scal = Avec + 1024;                  // [2] (+pad)
  int*   flags = (int*)(scal + 16);           // [8*64] stamped flags

  float* out_main   = (float*)d_out;            // [512,1000]
  float* out_skills = (float*)d_out + QQ * NN;  // [1000,128]

  // Zero all layer flags (captured in graph; re-zeroed every replay).
  hipMemsetAsync(flags, 0, LAYERS * 64 * sizeof(int), stream);

  // X = inputs @ W_inp^T + b_inp   (M=512, K=1000, R=1024, ldc=HPAD)
  gemm_nt<<<dim3(HPAD / 64, QQ / 64), 256, 0, stream>>>(
      inputs, W_inp, b_inp, X, QQ, NN, HPAD, NN, HPAD);

  // List-scheduled wavefront, capped at CONC pairs/stage. Gate GEMMs fused
  // into lstm_stage Phase A (inputs complete by stage ordering).
  bool donep[LAYERS][CHUNKS] = {};
  int remaining = LAYERS * CHUNKS;
  while (remaining > 0) {
    int pl[CONC], pcid[CONC];
    bool sel[LAYERS][CHUNKS] = {};
    int np = 0;
    for (int pick = 0; pick < CONC; pick++) {
      int bl = -1, bc = -1, bkey = 1 << 30;
      for (int l = 0; l < LAYERS; l++)
        for (int c = 0; c < CHUNKS; c++) {
          if (donep[l][c] || sel[l][c]) continue;
          if (l > 0 && !donep[l - 1][c]) continue;
          if (c > 0 && !donep[l][c - 1]) continue;
          int key = (l + c) * 16 + (LAYERS - 1 - l);
          if (key < bkey) { bkey = key; bl = l; bc = c; }
        }
      if (bl < 0) break;
      sel[bl][bc] = true; pl[np] = bl; pcid[np] = bc; np++;
    }
    RArgs ra;
    for (int i = 0; i < np; i++) {
      int l = pl[i], c = pcid[i];
      RPair& r = ra.p[i];
      if (l == 0) {
        r.Hin = X; r.Wih = W_ih0; r.b1 = b_ih0; r.b2 = b_hh0;
        r.Whh = W_hh0; r.kin = HHID;
      } else {
        r.Hin = H + (size_t)(l - 1) * QQ * HPAD;
        r.Wih = W_ih + (size_t)(l - 1) * G4 * NN;
        r.b1 = b_ih + (size_t)(l - 1) * G4;
        r.b2 = b_hh + (size_t)(l - 1) * G4;
        r.Whh = W_hh + (size_t)(l - 1) * G4 * NN;
        r.kin = NN;
      }
      r.Hout = H + (size_t)l * QQ * HPAD;
      r.flag = flags + l * 64;
      r.Call = Call + l * HPAD;
      r.t0 = c * TC;
    }
    for (int i = np; i < CONC; i++) ra.p[i] = ra.p[0];
    lstm_stage<<<dim3(LBLK, np), 1024, 0, stream>>>(ra);
    for (int i = 0; i < np; i++) donep[pl[i]][pcid[i]] = true;
    remaining -= np;
  }

  float* H7 = H + (size_t)7 * QQ * HPAD;
  epilogue_out<<<QQ, 256, 0, stream>>>(H7, W_lin, b_lin, ccol, D_nz,
                                       out_main, irb, mnir);
  reduce_scalars<<<1, 512, 0, stream>>>(irb, mnir, scal);
  accum_A<<<4, 256, 0, stream>>>(H7, irb, Avec);
  skills_out<<<(NN * CCON) / 256, 256, 0, stream>>>(Avec, W_lin, b_lin, scal,
                                                    out_skills);
}